// Round 3
// baseline (212.614 us; speedup 1.0000x reference)
//
#include <hip/hip_runtime.h>

// ---------------- types ----------------
typedef __bf16 bf16_8 __attribute__((ext_vector_type(8)));
typedef __bf16 bf16_4 __attribute__((ext_vector_type(4)));
typedef float  f32_4  __attribute__((ext_vector_type(4)));
typedef short  s16x4  __attribute__((ext_vector_type(4)));

typedef __attribute__((address_space(1))) const void* as1_cvp;
typedef __attribute__((address_space(3))) void*       as3_vp;

__device__ __forceinline__ void load16_to_lds(const void* g, void* l) {
    __builtin_amdgcn_global_load_lds((as1_cvp)g, (as3_vp)l, 16, 0, 0);
}

__device__ __forceinline__ f32_4 mfma16x16x16(bf16_4 a, bf16_4 b, f32_4 c) {
#if __has_builtin(__builtin_amdgcn_mfma_f32_16x16x16_bf16)
    return __builtin_amdgcn_mfma_f32_16x16x16_bf16(a, b, c, 0, 0, 0);
#else
    return __builtin_amdgcn_mfma_f32_16x16x16bf16_1k(
        __builtin_bit_cast(s16x4, a), __builtin_bit_cast(s16x4, b), c, 0, 0, 0);
#endif
}

// hardware 2^x (v_exp_f32); scale log2(e) is folded into Q at load time
__device__ __forceinline__ float fast_exp2(float x) {
#if __has_builtin(__builtin_amdgcn_exp2f)
    return __builtin_amdgcn_exp2f(x);
#else
    return exp2f(x);
#endif
}

// ---------------- fused fp32 -> bf16 convert (x | Wqkv | Wproj) ----------------
__global__ __launch_bounds__(256) void cvt_all(
    const float* __restrict__ a, const float* __restrict__ b,
    const float* __restrict__ c, __bf16* __restrict__ out,
    int na4, int nb4, int nc4)
{
    int i = blockIdx.x * 256 + threadIdx.x;
    if (i >= na4 + nb4 + nc4) return;
    float4 f;
    if (i < na4)            f = ((const float4*)a)[i];
    else if (i < na4 + nb4) f = ((const float4*)b)[i - na4];
    else                    f = ((const float4*)c)[i - na4 - nb4];
    bf16_4 v = { (__bf16)f.x, (__bf16)f.y, (__bf16)f.z, (__bf16)f.w };
    ((bf16_4*)out)[i] = v;
}

// ---------------- bf16 GEMM: C[M,N] = A[M,K] * B[N,K]^T + bias ----------------
// QKV==1: N=3072 logical; cols <2048 (Q|K) stored to Cb with row stride ldc=2048;
// cols >=2048 (V) stored TRANSPOSED to Vtb as [b][h*64+d][t] directly from
// accumulators (the 4 acc elems per lane are contiguous t in V^T -> b64 stores).
#define BM 128

template<int OUT_BF16, int BN_, int QKV>
__global__ __launch_bounds__(256) void gemm_bt(
    const __bf16* __restrict__ A,   // [M,K]
    const __bf16* __restrict__ B,   // [N,K]
    const float*  __restrict__ bias,// [N] or nullptr
    __bf16* __restrict__ Cb, float* __restrict__ Cf,
    __bf16* __restrict__ Vtb,
    int M, int N, int K, int ldc)
{
    constexpr int NT   = BN_ / 32;
    constexpr int CSTR = BN_ + (OUT_BF16 ? 8 : 4);
    __shared__ __align__(16) char smem[35840];
    __bf16* As = (__bf16*)smem;          // [128][64]
    __bf16* Bs = As + 128 * 64;          // [BN_][64]

    const int tid  = threadIdx.x;
    const int wave = tid >> 6;
    const int lane = tid & 63;
    const int wm = wave >> 1, wn = wave & 1;
    const int quad = lane >> 4, l16 = lane & 15;
    const int bm = blockIdx.y * BM, bn = blockIdx.x * BN_;

    const int r0 = tid >> 3;
    const int ch = tid & 7;
    const int cs = (ch ^ (r0 & 7)) * 8;

    f32_4 acc[4][NT];
    #pragma unroll
    for (int i = 0; i < 4; ++i)
        #pragma unroll
        for (int j = 0; j < NT; ++j)
            acc[i][j] = f32_4{0.f, 0.f, 0.f, 0.f};

    for (int k0 = 0; k0 < K; k0 += 64) {
        __syncthreads();
        #pragma unroll
        for (int p = 0; p < 4; ++p) {
            int row = p * 32 + r0;
            load16_to_lds(A + (size_t)(bm + row) * K + k0 + cs,
                          &As[(p * 32 + wave * 8) * 64]);
        }
        #pragma unroll
        for (int p = 0; p < BN_ / 32; ++p) {
            int row = p * 32 + r0;
            load16_to_lds(B + (size_t)(bn + row) * K + k0 + cs,
                          &Bs[(p * 32 + wave * 8) * 64]);
        }
        __syncthreads();

        #pragma unroll
        for (int h = 0; h < 2; ++h) {
            const int sl = ((quad + h * 4) ^ (l16 & 7)) * 8;
            bf16_8 af[4], bfr[NT];
            #pragma unroll
            for (int mt = 0; mt < 4; ++mt)
                af[mt] = *(const bf16_8*)&As[(wm * 64 + mt * 16 + l16) * 64 + sl];
            #pragma unroll
            for (int nt = 0; nt < NT; ++nt)
                bfr[nt] = *(const bf16_8*)&Bs[(wn * (BN_/2) + nt * 16 + l16) * 64 + sl];
            #pragma unroll
            for (int mt = 0; mt < 4; ++mt)
                #pragma unroll
                for (int nt = 0; nt < NT; ++nt)
                    acc[mt][nt] = __builtin_amdgcn_mfma_f32_16x16x32_bf16(
                        af[mt], bfr[nt], acc[mt][nt], 0, 0, 0);
        }
    }

    if (QKV && bn >= 2048) {
        // ---- V tile: store transposed directly (V^T[b][h*64+d][t]) ----
        const int b_ = bm >> 11;
        const int t0 = (bm & 2047) + wm * 64;
        #pragma unroll
        for (int nt = 0; nt < NT; ++nt) {
            int vrow = (bn - 2048) + wn * (BN_/2) + nt * 16 + l16;   // h*64+d
            float bv = bias ? bias[2048 + vrow] : 0.f;
            #pragma unroll
            for (int mt = 0; mt < 4; ++mt) {
                bf16_4 ov;
                #pragma unroll
                for (int r = 0; r < 4; ++r)
                    ov[r] = (__bf16)(acc[mt][nt][r] + bv);
                *(bf16_4*)(Vtb + ((size_t)b_ * 1024 + vrow) * 2048
                           + t0 + mt * 16 + quad * 4) = ov;
            }
        }
        return;
    }

    __syncthreads();

    if (OUT_BF16) {
        __bf16* Cs = (__bf16*)smem;
        #pragma unroll
        for (int mt = 0; mt < 4; ++mt)
            #pragma unroll
            for (int nt = 0; nt < NT; ++nt) {
                int col = wn * (BN_/2) + nt * 16 + l16;
                float bv = bias ? bias[bn + col] : 0.f;
                #pragma unroll
                for (int r = 0; r < 4; ++r)
                    Cs[(wm * 64 + mt * 16 + quad * 4 + r) * CSTR + col] =
                        (__bf16)(acc[mt][nt][r] + bv);
            }
        __syncthreads();
        const int rr = tid >> 4, cc = (tid & 15) * 8;
        #pragma unroll
        for (int p = 0; p < 8; ++p) {
            int row = p * 16 + rr;
            bf16_8 v = *(const bf16_8*)&Cs[row * CSTR + cc];
            *(bf16_8*)(Cb + (size_t)(bm + row) * ldc + bn + cc) = v;
        }
    } else {
        float* Cs = (float*)smem;
        #pragma unroll
        for (int mt = 0; mt < 4; ++mt)
            #pragma unroll
            for (int nt = 0; nt < NT; ++nt) {
                int col = wn * (BN_/2) + nt * 16 + l16;
                float bv = bias ? bias[bn + col] : 0.f;
                #pragma unroll
                for (int r = 0; r < 4; ++r)
                    Cs[(wm * 64 + mt * 16 + quad * 4 + r) * CSTR + col] =
                        acc[mt][nt][r] + bv;
            }
        __syncthreads();
        const int rr = tid >> 4, cc = (tid & 15) * 4;
        #pragma unroll
        for (int p = 0; p < 8; ++p) {
            int row = p * 16 + rr;
            float4 v = *(const float4*)&Cs[row * CSTR + cc];
            *(float4*)(Cf + (size_t)(bm + row) * ldc + bn + cc) = v;
        }
    }
}

// ---------------- causal flash attention v9 ----------------
// v8 + wave re-decomposition: (wq=2 q-waves) x (wg=4 key-waves) instead of
// (4 x 2). Each wave: mt=4 q-tiles (64 rows), nt=1 key-frag (16 keys).
// K/V LDS fragments amortized over 4 Q-tiles -> 6 LDS reads/wave/iter
// (2x ds_read_b128 + 4x ds_read_b64) instead of 12. MFMA/exp work per wave
// unchanged (8x 16x16x32 QK + 16x 16x16x16 PV). Theory: attn is LDS-issue
// bound (MfmaUtil 23% == LDS-cycle ratio); halving LDS ops lifts it.
// Epilogue: 4-way wg merge (sequential adds, 3 extra barriers).
__global__ __launch_bounds__(512, 4) void attn_kernel(
    const __bf16* __restrict__ qk, const __bf16* __restrict__ vt,
    __bf16* __restrict__ out)
{
    constexpr int T = 2048;
    __shared__ __align__(16) char pool[35328];
    __bf16* Ks = (__bf16*)pool;             // [2][64*64] chunk-swizzled
    __bf16* Vt = (__bf16*)(pool + 16384);   // [2][64*64] chunk-swizzled (rows=d)
    float*  Om = (float*)pool;              // alias: [128][68] (34816 B)
    float*  Lm = (float*)(pool + 34816);    // [128]

    const int tid  = threadIdx.x;
    const int wave = tid >> 6;
    const int lane = tid & 63;
    const int wg = wave >> 1, wq = wave & 1;   // wg: 4-way key split, wq: 2-way q split
    const int quad = lane >> 4, l16 = lane & 15;

    const int fid  = blockIdx.x;            // 0..511
    const int xcd  = fid & 7;
    const int half = fid >> 8;
    const int w    = (fid >> 3) & 31;       // 0..31
    const int qt   = half ? (7 - (w >> 2)) : ((w >> 2) + 8);
    const int bh   = xcd * 4 + (w & 3);     // 0..31
    const int b = bh >> 4, h = bh & 15;
    const int jmax = 2 * qt + 1;

    const size_t rowbase = (size_t)b * T;
    const __bf16* Kbase = qk + 1024 + h * 64;            // row stride 2048
    const __bf16* Vbase = vt + (size_t)bh * 64 * 2048;   // [d][t]

    const int srow = tid >> 3;              // 0..63
    const int sch  = tid & 7;
    const int schf = sch ^ (srow & 7);      // fetched chunk (swizzle)

    // ---- Q fragments (B-operand of S^T); scale/sqrt(hd) AND log2(e) folded ----
    constexpr float QSCALE = 0.125f * 1.4426950408889634f;
    bf16_8 aq[4][2];
    #pragma unroll
    for (int mt = 0; mt < 4; ++mt) {
        const __bf16* qrow =
            qk + (rowbase + qt * 128 + wq * 64 + mt * 16 + l16) * 2048 + h * 64;
        aq[mt][0] = *(const bf16_8*)(qrow + quad * 8);
        aq[mt][1] = *(const bf16_8*)(qrow + 32 + quad * 8);
        #pragma unroll
        for (int u = 0; u < 8; ++u) {
            aq[mt][0][u] = (__bf16)((float)aq[mt][0][u] * QSCALE);
            aq[mt][1][u] = (__bf16)((float)aq[mt][1][u] * QSCALE);
        }
    }

    // ---- prologue: stage tile j=0 into buf 0 ----
    load16_to_lds(Kbase + (rowbase + srow) * 2048 + schf * 8, &Ks[wave * 512]);
    load16_to_lds(Vbase + (size_t)srow * 2048 + schf * 8,     &Vt[wave * 512]);

    float l_i[4] = {0.f, 0.f, 0.f, 0.f};
    f32_4 O[4][4];
    #pragma unroll
    for (int mt = 0; mt < 4; ++mt)
        #pragma unroll
        for (int dt = 0; dt < 4; ++dt) O[mt][dt] = f32_4{0.f, 0.f, 0.f, 0.f};

    for (int j = 0; j <= jmax; ++j) {
        const int cur = j & 1, nxt = cur ^ 1;
        __syncthreads();   // buf[cur] staged; buf[nxt] reads complete

        if (j < jmax) {
            const int jn = j + 1;
            load16_to_lds(Kbase + (rowbase + jn * 64 + srow) * 2048 + schf * 8,
                          &Ks[nxt * 4096 + wave * 512]);
            load16_to_lds(Vbase + (size_t)srow * 2048 + jn * 64 + schf * 8,
                          &Vt[nxt * 4096 + wave * 512]);
        }

        // ---- S^T = K (Q*qscale)^T : A=K-frag (16 keys, wg split), B=Q-frag ----
        const int rk = wg * 16 + l16;
        const int rx = rk & 7;
        f32_4 S[4];
        __builtin_amdgcn_s_setprio(1);
        {
            bf16_8 kb0 = *(const bf16_8*)&Ks[cur * 4096 + rk * 64 + ((quad ^ rx) << 3)];
            bf16_8 kb1 = *(const bf16_8*)&Ks[cur * 4096 + rk * 64 + (((quad + 4) ^ rx) << 3)];
            #pragma unroll
            for (int mt = 0; mt < 4; ++mt) {
                f32_4 zz = {0.f, 0.f, 0.f, 0.f};
                zz = __builtin_amdgcn_mfma_f32_16x16x32_bf16(kb0, aq[mt][0], zz, 0, 0, 0);
                zz = __builtin_amdgcn_mfma_f32_16x16x32_bf16(kb1, aq[mt][1], zz, 0, 0, 0);
                S[mt] = zz;
            }
        }
        __builtin_amdgcn_s_setprio(0);

        // ---- exp2 + causal mask; P^T stays in registers as x16 B-frags ----
        const bool diag = (j >= 2 * qt);
        bf16_4 bp[4];   // [mt]
        #pragma unroll
        for (int mt = 0; mt < 4; ++mt) {
            int qg = qt * 128 + wq * 64 + mt * 16 + l16;
            #pragma unroll
            for (int rr = 0; rr < 4; ++rr) {
                float p = fast_exp2(S[mt][rr]);
                if (diag) {
                    int key = j * 64 + wg * 16 + quad * 4 + rr;
                    if (key > qg) p = 0.f;
                }
                l_i[mt] += p;
                bp[mt][rr] = (__bf16)p;
            }
        }

        // ---- O^T += V^T P^T  (x16 MFMAs; A-frags b64 from swizzled Vt) ----
        __builtin_amdgcn_s_setprio(1);
        #pragma unroll
        for (int dt = 0; dt < 4; ++dt) {
            int d = dt * 16 + l16;
            int dsw = d & 7;
            int chv = (wg * 2 + (quad >> 1)) ^ dsw;
            bf16_4 vaf = *(const bf16_4*)&Vt[cur * 4096 + d * 64 + chv * 8 + (quad & 1) * 4];
            #pragma unroll
            for (int mt = 0; mt < 4; ++mt)
                O[mt][dt] = mfma16x16x16(vaf, bp[mt], O[mt][dt]);
        }
        __builtin_amdgcn_s_setprio(0);
    }

    // ---- reduce l across quads ----
    float lw[4];
    #pragma unroll
    for (int mt = 0; mt < 4; ++mt) {
        float v = l_i[mt];
        v += __shfl_xor(v, 16, 64);
        v += __shfl_xor(v, 32, 64);
        lw[mt] = v;
    }

    // ---- 4-way wg merge via LDS (sequential adds) ----
    __syncthreads();   // all Ks/Vt reads done before Om aliases the pool
    if (wg == 3) {
        #pragma unroll
        for (int mt = 0; mt < 4; ++mt) {
            int row = wq * 64 + mt * 16 + l16;
            #pragma unroll
            for (int dt = 0; dt < 4; ++dt)
                *(f32_4*)&Om[row * 68 + dt * 16 + quad * 4] = O[mt][dt];
            if (quad == 0) Lm[row] = lw[mt];
        }
    }
    __syncthreads();
    if (wg == 2) {
        #pragma unroll
        for (int mt = 0; mt < 4; ++mt) {
            int row = wq * 64 + mt * 16 + l16;
            #pragma unroll
            for (int dt = 0; dt < 4; ++dt) {
                f32_4 o2 = *(const f32_4*)&Om[row * 68 + dt * 16 + quad * 4];
                #pragma unroll
                for (int rr = 0; rr < 4; ++rr) o2[rr] += O[mt][dt][rr];
                *(f32_4*)&Om[row * 68 + dt * 16 + quad * 4] = o2;
            }
            if (quad == 0) Lm[row] += lw[mt];
        }
    }
    __syncthreads();
    if (wg == 1) {
        #pragma unroll
        for (int mt = 0; mt < 4; ++mt) {
            int row = wq * 64 + mt * 16 + l16;
            #pragma unroll
            for (int dt = 0; dt < 4; ++dt) {
                f32_4 o2 = *(const f32_4*)&Om[row * 68 + dt * 16 + quad * 4];
                #pragma unroll
                for (int rr = 0; rr < 4; ++rr) o2[rr] += O[mt][dt][rr];
                *(f32_4*)&Om[row * 68 + dt * 16 + quad * 4] = o2;
            }
            if (quad == 0) Lm[row] += lw[mt];
        }
    }
    __syncthreads();
    if (wg == 0) {
        #pragma unroll
        for (int mt = 0; mt < 4; ++mt) {
            int row = wq * 64 + mt * 16 + l16;
            float inv = 1.f / (lw[mt] + Lm[row]);
            int q = qt * 128 + row;
            #pragma unroll
            for (int dt = 0; dt < 4; ++dt) {
                f32_4 o2 = *(const f32_4*)&Om[row * 68 + dt * 16 + quad * 4];
                bf16_4 ov;
                #pragma unroll
                for (int rr = 0; rr < 4; ++rr)
                    ov[rr] = (__bf16)((O[mt][dt][rr] + o2[rr]) * inv);
                *(bf16_4*)(out + (rowbase + q) * 1024 + h * 64 + dt * 16 + quad * 4) = ov;
            }
        }
    }
}

// ---------------- launch ----------------
extern "C" void kernel_launch(void* const* d_in, const int* in_sizes, int n_in,
                              void* d_out, int out_size, void* d_ws, size_t ws_size,
                              hipStream_t stream)
{
    constexpr int Bc = 2, Tc = 2048, Dc = 1024;
    constexpr int M  = Bc * Tc;
    constexpr int N1 = 3 * Dc;

    const float* x     = (const float*)d_in[0];
    const float* Wqkv  = (const float*)d_in[1];
    const float* bqkv  = (const float*)d_in[2];
    const float* Wproj = (const float*)d_in[3];
    const float* bproj = (const float*)d_in[4];
    float* outp = (float*)d_out;

    __bf16* xb     = (__bf16*)d_ws;                        // 4096*1024
    __bf16* wqkvb  = xb     + (size_t)M * Dc;              // 3072*1024
    __bf16* wprojb = wqkvb  + (size_t)N1 * Dc;             // 1024*1024
    __bf16* qkb    = wprojb + (size_t)Dc * Dc;             // 4096*2048 (Q|K)
    __bf16* vtb    = qkb    + (size_t)M * 2048;            // 2*1024*2048 (V^T)
    __bf16* attnb  = vtb    + (size_t)Bc * 1024 * 2048;    // 4096*1024

    {
        int na4 = M * Dc / 4, nb4 = N1 * Dc / 4, nc4 = Dc * Dc / 4;
        int n4 = na4 + nb4 + nc4;
        cvt_all<<<(n4 + 255) / 256, 256, 0, stream>>>(x, Wqkv, Wproj, xb, na4, nb4, nc4);
    }

    gemm_bt<1, 128, 1><<<dim3(N1 / 128, M / BM), 256, 0, stream>>>(
        xb, wqkvb, bqkv, qkb, nullptr, vtb, M, N1, Dc, 2048);

    attn_kernel<<<dim3(512), 512, 0, stream>>>(qkb, vtb, attnb);

    gemm_bt<0, 64, 0><<<dim3(Dc / 64, M / BM), 256, 0, stream>>>(
        attnb, wprojb, bproj, nullptr, outp, nullptr, M, Dc, Dc, Dc);
}

// Round 4
// 176.144 us; speedup vs baseline: 1.2070x; 1.2070x over previous
//
#include <hip/hip_runtime.h>

// ---------------- types ----------------
typedef __bf16 bf16_8 __attribute__((ext_vector_type(8)));
typedef __bf16 bf16_4 __attribute__((ext_vector_type(4)));
typedef __bf16 bf16_2 __attribute__((ext_vector_type(2)));
typedef float  f32_4  __attribute__((ext_vector_type(4)));
typedef float  f32_16 __attribute__((ext_vector_type(16)));

typedef __attribute__((address_space(1))) const void* as1_cvp;
typedef __attribute__((address_space(3))) void*       as3_vp;

__device__ __forceinline__ void load16_to_lds(const void* g, void* l) {
    __builtin_amdgcn_global_load_lds((as1_cvp)g, (as3_vp)l, 16, 0, 0);
}

// hardware 2^x (v_exp_f32); scale log2(e) is folded into Q at load time
__device__ __forceinline__ float fast_exp2(float x) {
#if __has_builtin(__builtin_amdgcn_exp2f)
    return __builtin_amdgcn_exp2f(x);
#else
    return exp2f(x);
#endif
}

// pack two f32 -> one dword of 2 bf16 (compiler emits cvt+pack)
__device__ __forceinline__ unsigned pk2(float lo, float hi) {
    union { bf16_2 h; unsigned u; } t;
    t.h = bf16_2{(__bf16)lo, (__bf16)hi};
    return t.u;
}

// v_permlane32_swap_b32: a <- [a.lo | b.lo], b <- [a.hi | b.hi]
__device__ __forceinline__ void pswap(unsigned &a, unsigned &b) {
    asm("v_permlane32_swap_b32 %0, %1" : "+v"(a), "+v"(b));
}

// ---------------- fused fp32 -> bf16 convert (x | Wqkv | Wproj) ----------------
__global__ __launch_bounds__(256) void cvt_all(
    const float* __restrict__ a, const float* __restrict__ b,
    const float* __restrict__ c, __bf16* __restrict__ out,
    int na4, int nb4, int nc4)
{
    int i = blockIdx.x * 256 + threadIdx.x;
    if (i >= na4 + nb4 + nc4) return;
    float4 f;
    if (i < na4)            f = ((const float4*)a)[i];
    else if (i < na4 + nb4) f = ((const float4*)b)[i - na4];
    else                    f = ((const float4*)c)[i - na4 - nb4];
    bf16_4 v = { (__bf16)f.x, (__bf16)f.y, (__bf16)f.z, (__bf16)f.w };
    ((bf16_4*)out)[i] = v;
}

// ---------------- bf16 GEMM: C[M,N] = A[M,K] * B[N,K]^T + bias ----------------
// QKV==1: N=3072 logical; cols <2048 (Q|K) stored to Cb with row stride ldc=2048;
// cols >=2048 (V) stored TRANSPOSED to Vtb as [b][h*64+d][t] directly from
// accumulators (the 4 acc elems per lane are contiguous t in V^T -> b64 stores).
#define BM 128

template<int OUT_BF16, int BN_, int QKV>
__global__ __launch_bounds__(256) void gemm_bt(
    const __bf16* __restrict__ A,   // [M,K]
    const __bf16* __restrict__ B,   // [N,K]
    const float*  __restrict__ bias,// [N] or nullptr
    __bf16* __restrict__ Cb, float* __restrict__ Cf,
    __bf16* __restrict__ Vtb,
    int M, int N, int K, int ldc)
{
    constexpr int NT   = BN_ / 32;
    constexpr int CSTR = BN_ + (OUT_BF16 ? 8 : 4);
    __shared__ __align__(16) char smem[35840];
    __bf16* As = (__bf16*)smem;          // [128][64]
    __bf16* Bs = As + 128 * 64;          // [BN_][64]

    const int tid  = threadIdx.x;
    const int wave = tid >> 6;
    const int lane = tid & 63;
    const int wm = wave >> 1, wn = wave & 1;
    const int quad = lane >> 4, l16 = lane & 15;
    const int bm = blockIdx.y * BM, bn = blockIdx.x * BN_;

    const int r0 = tid >> 3;
    const int ch = tid & 7;
    const int cs = (ch ^ (r0 & 7)) * 8;

    f32_4 acc[4][NT];
    #pragma unroll
    for (int i = 0; i < 4; ++i)
        #pragma unroll
        for (int j = 0; j < NT; ++j)
            acc[i][j] = f32_4{0.f, 0.f, 0.f, 0.f};

    for (int k0 = 0; k0 < K; k0 += 64) {
        __syncthreads();
        #pragma unroll
        for (int p = 0; p < 4; ++p) {
            int row = p * 32 + r0;
            load16_to_lds(A + (size_t)(bm + row) * K + k0 + cs,
                          &As[(p * 32 + wave * 8) * 64]);
        }
        #pragma unroll
        for (int p = 0; p < BN_ / 32; ++p) {
            int row = p * 32 + r0;
            load16_to_lds(B + (size_t)(bn + row) * K + k0 + cs,
                          &Bs[(p * 32 + wave * 8) * 64]);
        }
        __syncthreads();

        #pragma unroll
        for (int h = 0; h < 2; ++h) {
            const int sl = ((quad + h * 4) ^ (l16 & 7)) * 8;
            bf16_8 af[4], bfr[NT];
            #pragma unroll
            for (int mt = 0; mt < 4; ++mt)
                af[mt] = *(const bf16_8*)&As[(wm * 64 + mt * 16 + l16) * 64 + sl];
            #pragma unroll
            for (int nt = 0; nt < NT; ++nt)
                bfr[nt] = *(const bf16_8*)&Bs[(wn * (BN_/2) + nt * 16 + l16) * 64 + sl];
            #pragma unroll
            for (int mt = 0; mt < 4; ++mt)
                #pragma unroll
                for (int nt = 0; nt < NT; ++nt)
                    acc[mt][nt] = __builtin_amdgcn_mfma_f32_16x16x32_bf16(
                        af[mt], bfr[nt], acc[mt][nt], 0, 0, 0);
        }
    }

    if (QKV && bn >= 2048) {
        // ---- V tile: store transposed directly (V^T[b][h*64+d][t]) ----
        const int b_ = bm >> 11;
        const int t0 = (bm & 2047) + wm * 64;
        #pragma unroll
        for (int nt = 0; nt < NT; ++nt) {
            int vrow = (bn - 2048) + wn * (BN_/2) + nt * 16 + l16;   // h*64+d
            float bv = bias ? bias[2048 + vrow] : 0.f;
            #pragma unroll
            for (int mt = 0; mt < 4; ++mt) {
                bf16_4 ov;
                #pragma unroll
                for (int r = 0; r < 4; ++r)
                    ov[r] = (__bf16)(acc[mt][nt][r] + bv);
                *(bf16_4*)(Vtb + ((size_t)b_ * 1024 + vrow) * 2048
                           + t0 + mt * 16 + quad * 4) = ov;
            }
        }
        return;
    }

    __syncthreads();

    if (OUT_BF16) {
        __bf16* Cs = (__bf16*)smem;
        #pragma unroll
        for (int mt = 0; mt < 4; ++mt)
            #pragma unroll
            for (int nt = 0; nt < NT; ++nt) {
                int col = wn * (BN_/2) + nt * 16 + l16;
                float bv = bias ? bias[bn + col] : 0.f;
                #pragma unroll
                for (int r = 0; r < 4; ++r)
                    Cs[(wm * 64 + mt * 16 + quad * 4 + r) * CSTR + col] =
                        (__bf16)(acc[mt][nt][r] + bv);
            }
        __syncthreads();
        const int rr = tid >> 4, cc = (tid & 15) * 8;
        #pragma unroll
        for (int p = 0; p < 8; ++p) {
            int row = p * 16 + rr;
            bf16_8 v = *(const bf16_8*)&Cs[row * CSTR + cc];
            *(bf16_8*)(Cb + (size_t)(bm + row) * ldc + bn + cc) = v;
        }
    } else {
        float* Cs = (float*)smem;
        #pragma unroll
        for (int mt = 0; mt < 4; ++mt)
            #pragma unroll
            for (int nt = 0; nt < NT; ++nt) {
                int col = wn * (BN_/2) + nt * 16 + l16;
                float bv = bias ? bias[bn + col] : 0.f;
                #pragma unroll
                for (int r = 0; r < 4; ++r)
                    Cs[(wm * 64 + mt * 16 + quad * 4 + r) * CSTR + col] =
                        acc[mt][nt][r] + bv;
            }
        __syncthreads();
        const int rr = tid >> 4, cc = (tid & 15) * 4;
        #pragma unroll
        for (int p = 0; p < 8; ++p) {
            int row = p * 16 + rr;
            float4 v = *(const float4*)&Cs[row * CSTR + cc];
            *(float4*)(Cf + (size_t)(bm + row) * ldc + bn + cc) = v;
        }
    }
}

// ---------------- causal flash attention v10: 32x32 MFMA ----------------
// 256 threads, 4 waves = wq(2, q-halves of 128-row band) x wg(2, key-halves).
// Each wave: 64 q x 32 keys per iter via 32x32x16 MFMAs.
// Per iter per wave LDS: 4 b128 (K A-frags) + 4 b128 (V A-frags) -- ~3x fewer
// LDS instrs than v8's 12 (4 b128 + 8 b64 per 32q x 32k).
// S^T C/D (32x32): col(q)=lane&31, row(key)=(reg&3)+8*(reg>>2)+4*(lane>>5).
// P^T rebuilt in-register as PV B-frags via bf16 pair-pack + permlane32_swap
// (one swap fills two B-frag dwords; VALU-only, zero LDS).
// VGPR ~150 -> __launch_bounds__(256,2): 2 waves/SIMD, 2 blocks/CU, balanced
// (qt+8, 7-qt) pairing as v8. Epilogue: 2-way wg merge via LDS (Om aliases pool).
__global__ __launch_bounds__(256, 2) void attn_kernel(
    const __bf16* __restrict__ qk, const __bf16* __restrict__ vt,
    __bf16* __restrict__ out)
{
    constexpr int T = 2048;
    __shared__ __align__(16) char pool[35328];
    __bf16* Ks = (__bf16*)pool;             // [2][64 keys][64 d] chunk-swizzled
    __bf16* Vt = (__bf16*)(pool + 16384);   // [2][64 d][64 t]  chunk-swizzled
    float*  Om = (float*)pool;              // alias: [128][68] f32
    float*  Lm = (float*)(pool + 34816);    // [128]

    const int tid  = threadIdx.x;
    const int wave = tid >> 6;
    const int lane = tid & 63;
    const int wq = wave & 1, wg = wave >> 1;
    const int l32 = lane & 31, hh = lane >> 5;

    const int fid  = blockIdx.x;            // 0..511
    const int xcd  = fid & 7;
    const int hsel = fid >> 8;
    const int w    = (fid >> 3) & 31;
    const int qt   = hsel ? (7 - (w >> 2)) : ((w >> 2) + 8);
    const int bh   = xcd * 4 + (w & 3);
    const int b = bh >> 4, h = bh & 15;
    const int jmax = 2 * qt + 1;

    const size_t rowbase = (size_t)b * T;
    const __bf16* Kbase = qk + 1024 + h * 64;            // row stride 2048
    const __bf16* Vbase = vt + (size_t)bh * 64 * 2048;   // [d][t]

    // staging: 2x load16 per thread per buffer (K: 64 rows x 8 chunks; V same)
    const int sr   = tid >> 3;              // 0..31
    const int schf = (tid & 7) ^ (sr & 7);  // (sr+32)&7 == sr&7

    // ---- Q fragments (B-operand), scale*log2(e) folded ----
    constexpr float QSCALE = 0.125f * 1.4426950408889634f;
    bf16_8 aq[2][4];   // [qtile][d-frag]
    #pragma unroll
    for (int qq = 0; qq < 2; ++qq)
        #pragma unroll
        for (int df = 0; df < 4; ++df) {
            const __bf16* qp = qk + (rowbase + qt*128 + wq*64 + qq*32 + l32)*2048
                               + h*64 + df*16 + hh*8;
            bf16_8 v = *(const bf16_8*)qp;
            #pragma unroll
            for (int u = 0; u < 8; ++u) v[u] = (__bf16)((float)v[u] * QSCALE);
            aq[qq][df] = v;
        }

    // ---- prologue: stage tile j=0 into buf 0 ----
    #pragma unroll
    for (int p = 0; p < 2; ++p) {
        load16_to_lds(Kbase + (rowbase + sr + 32*p)*2048 + schf*8,
                      Ks + p*2048 + wave*512);
        load16_to_lds(Vbase + (size_t)(sr + 32*p)*2048 + schf*8,
                      Vt + p*2048 + wave*512);
    }

    f32_16 O[2][2];   // [dtile][qtile]
    #pragma unroll
    for (int dt = 0; dt < 2; ++dt)
        #pragma unroll
        for (int qq = 0; qq < 2; ++qq)
            #pragma unroll
            for (int r = 0; r < 16; ++r) O[dt][qq][r] = 0.f;
    float l_i[2] = {0.f, 0.f};

    for (int j = 0; j <= jmax; ++j) {
        const int cur = j & 1, nxt = cur ^ 1;
        __syncthreads();   // buf[cur] staged; buf[nxt] reads complete

        if (j < jmax) {
            const int jn = j + 1;
            #pragma unroll
            for (int p = 0; p < 2; ++p) {
                load16_to_lds(Kbase + (rowbase + jn*64 + sr + 32*p)*2048 + schf*8,
                              Ks + nxt*4096 + p*2048 + wave*512);
                load16_to_lds(Vbase + (size_t)(sr + 32*p)*2048 + jn*64 + schf*8,
                              Vt + nxt*4096 + p*2048 + wave*512);
            }
        }

        // ---- S^T[32k x 64q] = K Q^T : A=K-frag, B=Q-frag, d-chained x4 ----
        const int krow = wg*32 + l32;
        const int ksw  = krow & 7;
        f32_16 S[2];
        __builtin_amdgcn_s_setprio(1);
        bf16_8 kf[4];
        #pragma unroll
        for (int df = 0; df < 4; ++df)
            kf[df] = *(const bf16_8*)&Ks[cur*4096 + krow*64 + (((2*df + hh) ^ ksw) << 3)];
        #pragma unroll
        for (int qq = 0; qq < 2; ++qq) {
            f32_16 z;
            #pragma unroll
            for (int r = 0; r < 16; ++r) z[r] = 0.f;
            #pragma unroll
            for (int df = 0; df < 4; ++df)
                z = __builtin_amdgcn_mfma_f32_32x32x16_bf16(kf[df], aq[qq][df], z, 0, 0, 0);
            S[qq] = z;
        }
        __builtin_amdgcn_s_setprio(0);

        // ---- exp2 + causal mask; pack P^T into PV B-frags (VALU only) ----
        const bool diag = (j >= 2*qt);
        unsigned fr[2][8];   // [qtile][khalf*4 + dword]
        #pragma unroll
        for (int qq = 0; qq < 2; ++qq) {
            float pe[16];
            const int qg = qt*128 + wq*64 + qq*32 + l32;
            #pragma unroll
            for (int r = 0; r < 16; ++r) {
                float e = fast_exp2(S[qq][r]);
                if (diag) {
                    int key = j*64 + wg*32 + (r&3) + 8*(r>>2) + 4*hh;
                    if (key > qg) e = 0.f;
                }
                pe[r] = e;
                l_i[qq] += e;
            }
            unsigned A = pk2(pe[0],  pe[1]),  Bv = pk2(pe[2],  pe[3]),
                     C = pk2(pe[4],  pe[5]),  D  = pk2(pe[6],  pe[7]),
                     E = pk2(pe[8],  pe[9]),  F  = pk2(pe[10], pe[11]),
                     G = pk2(pe[12], pe[13]), H  = pk2(pe[14], pe[15]);
            pswap(A, C); pswap(Bv, D); pswap(E, G); pswap(F, H);
            fr[qq][0] = A; fr[qq][1] = Bv; fr[qq][2] = C; fr[qq][3] = D;
            fr[qq][4] = E; fr[qq][5] = F;  fr[qq][6] = G; fr[qq][7] = H;
        }

        // ---- O^T += V^T P^T : A=V-frag (b128), B=P-frag (regs) ----
        __builtin_amdgcn_s_setprio(1);
        #pragma unroll
        for (int kh = 0; kh < 2; ++kh) {
            #pragma unroll
            for (int dt = 0; dt < 2; ++dt) {
                const int d = dt*32 + l32;
                bf16_8 vf = *(const bf16_8*)&Vt[cur*4096 + d*64 +
                                (((wg*4 + kh*2 + hh) ^ (d & 7)) << 3)];
                #pragma unroll
                for (int qq = 0; qq < 2; ++qq) {
                    union { unsigned dw[4]; bf16_8 v; } u;
                    u.dw[0] = fr[qq][kh*4+0]; u.dw[1] = fr[qq][kh*4+1];
                    u.dw[2] = fr[qq][kh*4+2]; u.dw[3] = fr[qq][kh*4+3];
                    O[dt][qq] = __builtin_amdgcn_mfma_f32_32x32x16_bf16(
                        vf, u.v, O[dt][qq], 0, 0, 0);
                }
            }
        }
        __builtin_amdgcn_s_setprio(0);
    }

    // ---- l: own 16 rows + partner half via xor-32 ----
    float lw[2];
    #pragma unroll
    for (int qq = 0; qq < 2; ++qq) {
        float v = l_i[qq];
        v += __shfl_xor(v, 32, 64);
        lw[qq] = v;
    }

    // ---- 2-way wg merge via LDS (Om aliases K/V pool) ----
    __syncthreads();   // all Ks/Vt reads done before Om aliases the pool
    if (wg == 1) {
        #pragma unroll
        for (int qq = 0; qq < 2; ++qq) {
            const int qrow = wq*64 + qq*32 + l32;
            #pragma unroll
            for (int dt = 0; dt < 2; ++dt)
                #pragma unroll
                for (int g = 0; g < 4; ++g) {
                    f32_4 t = { O[dt][qq][g*4+0], O[dt][qq][g*4+1],
                                O[dt][qq][g*4+2], O[dt][qq][g*4+3] };
                    *(f32_4*)&Om[qrow*68 + dt*32 + g*8 + hh*4] = t;
                }
            if (hh == 0) Lm[qrow] = lw[qq];
        }
    }
    __syncthreads();
    if (wg == 0) {
        #pragma unroll
        for (int qq = 0; qq < 2; ++qq) {
            const int qrow = wq*64 + qq*32 + l32;
            const float inv = 1.f / (lw[qq] + Lm[qrow]);
            const size_t obase = (rowbase + qt*128 + qrow) * 1024 + h*64;
            #pragma unroll
            for (int dt = 0; dt < 2; ++dt)
                #pragma unroll
                for (int g = 0; g < 4; ++g) {
                    f32_4 o2 = *(const f32_4*)&Om[qrow*68 + dt*32 + g*8 + hh*4];
                    bf16_4 ov;
                    #pragma unroll
                    for (int r = 0; r < 4; ++r)
                        ov[r] = (__bf16)((O[dt][qq][g*4+r] + o2[r]) * inv);
                    *(bf16_4*)(out + obase + dt*32 + g*8 + hh*4) = ov;
                }
        }
    }
}

// ---------------- launch ----------------
extern "C" void kernel_launch(void* const* d_in, const int* in_sizes, int n_in,
                              void* d_out, int out_size, void* d_ws, size_t ws_size,
                              hipStream_t stream)
{
    constexpr int Bc = 2, Tc = 2048, Dc = 1024;
    constexpr int M  = Bc * Tc;
    constexpr int N1 = 3 * Dc;

    const float* x     = (const float*)d_in[0];
    const float* Wqkv  = (const float*)d_in[1];
    const float* bqkv  = (const float*)d_in[2];
    const float* Wproj = (const float*)d_in[3];
    const float* bproj = (const float*)d_in[4];
    float* outp = (float*)d_out;

    __bf16* xb     = (__bf16*)d_ws;                        // 4096*1024
    __bf16* wqkvb  = xb     + (size_t)M * Dc;              // 3072*1024
    __bf16* wprojb = wqkvb  + (size_t)N1 * Dc;             // 1024*1024
    __bf16* qkb    = wprojb + (size_t)Dc * Dc;             // 4096*2048 (Q|K)
    __bf16* vtb    = qkb    + (size_t)M * 2048;            // 2*1024*2048 (V^T)
    __bf16* attnb  = vtb    + (size_t)Bc * 1024 * 2048;    // 4096*1024

    {
        int na4 = M * Dc / 4, nb4 = N1 * Dc / 4, nc4 = Dc * Dc / 4;
        int n4 = na4 + nb4 + nc4;
        cvt_all<<<(n4 + 255) / 256, 256, 0, stream>>>(x, Wqkv, Wproj, xb, na4, nb4, nc4);
    }

    gemm_bt<1, 128, 1><<<dim3(N1 / 128, M / BM), 256, 0, stream>>>(
        xb, wqkvb, bqkv, qkb, nullptr, vtb, M, N1, Dc, 2048);

    attn_kernel<<<dim3(512), 256, 0, stream>>>(qkb, vtb, attnb);

    gemm_bt<0, 64, 0><<<dim3(Dc / 64, M / BM), 256, 0, stream>>>(
        attnb, wprojb, bproj, nullptr, outp, nullptr, M, Dc, Dc, Dc);
}

// Round 5
// 163.954 us; speedup vs baseline: 1.2968x; 1.0744x over previous
//
#include <hip/hip_runtime.h>

// ---------------- types ----------------
typedef __bf16 bf16_8 __attribute__((ext_vector_type(8)));
typedef __bf16 bf16_4 __attribute__((ext_vector_type(4)));
typedef __bf16 bf16_2 __attribute__((ext_vector_type(2)));
typedef float  f32_4  __attribute__((ext_vector_type(4)));
typedef float  f32_16 __attribute__((ext_vector_type(16)));

typedef __attribute__((address_space(1))) const void* as1_cvp;
typedef __attribute__((address_space(3))) void*       as3_vp;

__device__ __forceinline__ void load16_to_lds(const void* g, void* l) {
    __builtin_amdgcn_global_load_lds((as1_cvp)g, (as3_vp)l, 16, 0, 0);
}

// hardware 2^x (v_exp_f32); scale log2(e) is folded into Q at load time
__device__ __forceinline__ float fast_exp2(float x) {
#if __has_builtin(__builtin_amdgcn_exp2f)
    return __builtin_amdgcn_exp2f(x);
#else
    return exp2f(x);
#endif
}

// pack two f32 -> one dword of 2 bf16 (compiler emits cvt+pack)
__device__ __forceinline__ unsigned pk2(float lo, float hi) {
    union { bf16_2 h; unsigned u; } t;
    t.h = bf16_2{(__bf16)lo, (__bf16)hi};
    return t.u;
}

// v_permlane32_swap_b32: a <- [a.lo | b.lo], b <- [a.hi | b.hi]
__device__ __forceinline__ void pswap(unsigned &a, unsigned &b) {
    asm("v_permlane32_swap_b32 %0, %1" : "+v"(a), "+v"(b));
}

// ---------------- fused fp32 -> bf16 convert (x | Wqkv | Wproj) ----------------
__global__ __launch_bounds__(256) void cvt_all(
    const float* __restrict__ a, const float* __restrict__ b,
    const float* __restrict__ c, __bf16* __restrict__ out,
    int na4, int nb4, int nc4)
{
    int i = blockIdx.x * 256 + threadIdx.x;
    if (i >= na4 + nb4 + nc4) return;
    float4 f;
    if (i < na4)            f = ((const float4*)a)[i];
    else if (i < na4 + nb4) f = ((const float4*)b)[i - na4];
    else                    f = ((const float4*)c)[i - na4 - nb4];
    bf16_4 v = { (__bf16)f.x, (__bf16)f.y, (__bf16)f.z, (__bf16)f.w };
    ((bf16_4*)out)[i] = v;
}

// ---------------- bf16 GEMM: C[M,N] = A[M,K] * B[N,K]^T + bias ----------------
// QKV==1: N=3072 logical; cols <2048 (Q|K) stored to Cb with row stride ldc=2048;
// cols >=2048 (V) stored TRANSPOSED to Vtb as [b][h*64+d][t] directly from
// accumulators (the 4 acc elems per lane are contiguous t in V^T -> b64 stores).
#define BM 128

template<int OUT_BF16, int BN_, int QKV>
__global__ __launch_bounds__(256) void gemm_bt(
    const __bf16* __restrict__ A,   // [M,K]
    const __bf16* __restrict__ B,   // [N,K]
    const float*  __restrict__ bias,// [N] or nullptr
    __bf16* __restrict__ Cb, float* __restrict__ Cf,
    __bf16* __restrict__ Vtb,
    int M, int N, int K, int ldc)
{
    constexpr int NT   = BN_ / 32;
    constexpr int CSTR = BN_ + (OUT_BF16 ? 8 : 4);
    __shared__ __align__(16) char smem[35840];
    __bf16* As = (__bf16*)smem;          // [128][64]
    __bf16* Bs = As + 128 * 64;          // [BN_][64]

    const int tid  = threadIdx.x;
    const int wave = tid >> 6;
    const int lane = tid & 63;
    const int wm = wave >> 1, wn = wave & 1;
    const int quad = lane >> 4, l16 = lane & 15;
    const int bm = blockIdx.y * BM, bn = blockIdx.x * BN_;

    const int r0 = tid >> 3;
    const int ch = tid & 7;
    const int cs = (ch ^ (r0 & 7)) * 8;

    f32_4 acc[4][NT];
    #pragma unroll
    for (int i = 0; i < 4; ++i)
        #pragma unroll
        for (int j = 0; j < NT; ++j)
            acc[i][j] = f32_4{0.f, 0.f, 0.f, 0.f};

    for (int k0 = 0; k0 < K; k0 += 64) {
        __syncthreads();
        #pragma unroll
        for (int p = 0; p < 4; ++p) {
            int row = p * 32 + r0;
            load16_to_lds(A + (size_t)(bm + row) * K + k0 + cs,
                          &As[(p * 32 + wave * 8) * 64]);
        }
        #pragma unroll
        for (int p = 0; p < BN_ / 32; ++p) {
            int row = p * 32 + r0;
            load16_to_lds(B + (size_t)(bn + row) * K + k0 + cs,
                          &Bs[(p * 32 + wave * 8) * 64]);
        }
        __syncthreads();

        #pragma unroll
        for (int h = 0; h < 2; ++h) {
            const int sl = ((quad + h * 4) ^ (l16 & 7)) * 8;
            bf16_8 af[4], bfr[NT];
            #pragma unroll
            for (int mt = 0; mt < 4; ++mt)
                af[mt] = *(const bf16_8*)&As[(wm * 64 + mt * 16 + l16) * 64 + sl];
            #pragma unroll
            for (int nt = 0; nt < NT; ++nt)
                bfr[nt] = *(const bf16_8*)&Bs[(wn * (BN_/2) + nt * 16 + l16) * 64 + sl];
            #pragma unroll
            for (int mt = 0; mt < 4; ++mt)
                #pragma unroll
                for (int nt = 0; nt < NT; ++nt)
                    acc[mt][nt] = __builtin_amdgcn_mfma_f32_16x16x32_bf16(
                        af[mt], bfr[nt], acc[mt][nt], 0, 0, 0);
        }
    }

    if (QKV && bn >= 2048) {
        // ---- V tile: store transposed directly (V^T[b][h*64+d][t]) ----
        const int b_ = bm >> 11;
        const int t0 = (bm & 2047) + wm * 64;
        #pragma unroll
        for (int nt = 0; nt < NT; ++nt) {
            int vrow = (bn - 2048) + wn * (BN_/2) + nt * 16 + l16;   // h*64+d
            float bv = bias ? bias[2048 + vrow] : 0.f;
            #pragma unroll
            for (int mt = 0; mt < 4; ++mt) {
                bf16_4 ov;
                #pragma unroll
                for (int r = 0; r < 4; ++r)
                    ov[r] = (__bf16)(acc[mt][nt][r] + bv);
                *(bf16_4*)(Vtb + ((size_t)b_ * 1024 + vrow) * 2048
                           + t0 + mt * 16 + quad * 4) = ov;
            }
        }
        return;
    }

    __syncthreads();

    if (OUT_BF16) {
        __bf16* Cs = (__bf16*)smem;
        #pragma unroll
        for (int mt = 0; mt < 4; ++mt)
            #pragma unroll
            for (int nt = 0; nt < NT; ++nt) {
                int col = wn * (BN_/2) + nt * 16 + l16;
                float bv = bias ? bias[bn + col] : 0.f;
                #pragma unroll
                for (int r = 0; r < 4; ++r)
                    Cs[(wm * 64 + mt * 16 + quad * 4 + r) * CSTR + col] =
                        (__bf16)(acc[mt][nt][r] + bv);
            }
        __syncthreads();
        const int rr = tid >> 4, cc = (tid & 15) * 8;
        #pragma unroll
        for (int p = 0; p < 8; ++p) {
            int row = p * 16 + rr;
            bf16_8 v = *(const bf16_8*)&Cs[row * CSTR + cc];
            *(bf16_8*)(Cb + (size_t)(bm + row) * ldc + bn + cc) = v;
        }
    } else {
        float* Cs = (float*)smem;
        #pragma unroll
        for (int mt = 0; mt < 4; ++mt)
            #pragma unroll
            for (int nt = 0; nt < NT; ++nt) {
                int col = wn * (BN_/2) + nt * 16 + l16;
                float bv = bias ? bias[bn + col] : 0.f;
                #pragma unroll
                for (int r = 0; r < 4; ++r)
                    Cs[(wm * 64 + mt * 16 + quad * 4 + r) * CSTR + col] =
                        acc[mt][nt][r] + bv;
            }
        __syncthreads();
        const int rr = tid >> 4, cc = (tid & 15) * 4;
        #pragma unroll
        for (int p = 0; p < 8; ++p) {
            int row = p * 16 + rr;
            float4 v = *(const float4*)&Cs[row * CSTR + cc];
            *(float4*)(Cf + (size_t)(bm + row) * ldc + bn + cc) = v;
        }
    }
}

// ---------------- causal flash attention v11: 32x32 MFMA + counted vmcnt ----------------
// v10 compute (verified) + T4 pipeline: TRIPLE-buffered K/V staging with
// counted s_waitcnt vmcnt(4) + raw s_barrier instead of __syncthreads'
// vmcnt(0) drain. Tile j+2 is issued right after the barrier of iter j, so
// every load has ~2 full compute iterations to land -> HBM latency hidden
// even at 8 waves/CU. Final iteration waits vmcnt(0) (only its own tile in
// flight). Buffer safety: loads for buf[(j+2)%3] are issued only after the
// barrier at which all waves finished reading that buffer (iter j-1).
__global__ __launch_bounds__(256, 2) void attn_kernel(
    const __bf16* __restrict__ qk, const __bf16* __restrict__ vt,
    __bf16* __restrict__ out)
{
    constexpr int T = 2048;
    __shared__ __align__(16) char pool[49152];
    __bf16* Ks = (__bf16*)pool;             // [3][64 keys][64 d] chunk-swizzled
    __bf16* Vt = (__bf16*)(pool + 24576);   // [3][64 d][64 t]  chunk-swizzled
    float*  Om = (float*)pool;              // alias: [128][68] f32 (34816 B)
    float*  Lm = (float*)(pool + 34816);    // [128]

    const int tid  = threadIdx.x;
    const int wave = tid >> 6;
    const int lane = tid & 63;
    const int wq = wave & 1, wg = wave >> 1;
    const int l32 = lane & 31, hh = lane >> 5;

    const int fid  = blockIdx.x;            // 0..511
    const int xcd  = fid & 7;
    const int hsel = fid >> 8;
    const int w    = (fid >> 3) & 31;
    const int qt   = hsel ? (7 - (w >> 2)) : ((w >> 2) + 8);
    const int bh   = xcd * 4 + (w & 3);
    const int b = bh >> 4, h = bh & 15;
    const int jmax = 2 * qt + 1;

    const size_t rowbase = (size_t)b * T;
    const __bf16* Kbase = qk + 1024 + h * 64;            // row stride 2048
    const __bf16* Vbase = vt + (size_t)bh * 64 * 2048;   // [d][t]

    // staging: 4x load16 per thread per tile (2 K rows-chunks + 2 V)
    const int sr   = tid >> 3;              // 0..31
    const int schf = (tid & 7) ^ (sr & 7);  // (sr+32)&7 == sr&7

    // ---- Q fragments (B-operand), scale*log2(e) folded ----
    constexpr float QSCALE = 0.125f * 1.4426950408889634f;
    bf16_8 aq[2][4];   // [qtile][d-frag]
    #pragma unroll
    for (int qq = 0; qq < 2; ++qq)
        #pragma unroll
        for (int df = 0; df < 4; ++df) {
            const __bf16* qp = qk + (rowbase + qt*128 + wq*64 + qq*32 + l32)*2048
                               + h*64 + df*16 + hh*8;
            bf16_8 v = *(const bf16_8*)qp;
            #pragma unroll
            for (int u = 0; u < 8; ++u) v[u] = (__bf16)((float)v[u] * QSCALE);
            aq[qq][df] = v;
        }

    // ---- prologue: stage tiles 0 and 1 into bufs 0 and 1 ----
    #pragma unroll
    for (int t0 = 0; t0 < 2; ++t0)
        #pragma unroll
        for (int p = 0; p < 2; ++p) {
            load16_to_lds(Kbase + (rowbase + t0*64 + sr + 32*p)*2048 + schf*8,
                          Ks + t0*4096 + p*2048 + wave*512);
            load16_to_lds(Vbase + (size_t)(sr + 32*p)*2048 + t0*64 + schf*8,
                          Vt + t0*4096 + p*2048 + wave*512);
        }

    f32_16 O[2][2];   // [dtile][qtile]
    #pragma unroll
    for (int dt = 0; dt < 2; ++dt)
        #pragma unroll
        for (int qq = 0; qq < 2; ++qq)
            #pragma unroll
            for (int r = 0; r < 16; ++r) O[dt][qq][r] = 0.f;
    float l_i[2] = {0.f, 0.f};

    int cur = 0;       // buf index of tile j
    int sb  = 2;       // buf index of tile j+2 (stage target)
    for (int j = 0; j <= jmax; ++j) {
        // tile j staged? (its 4 loads are the oldest; tile j+1's 4 may fly)
        if (j < jmax) asm volatile("s_waitcnt vmcnt(4)" ::: "memory");
        else          asm volatile("s_waitcnt vmcnt(0)" ::: "memory");
        __builtin_amdgcn_s_barrier();   // all waves: tile j staged, buf[sb] reads done

        const int jn = j + 2;
        if (jn <= jmax) {
            #pragma unroll
            for (int p = 0; p < 2; ++p) {
                load16_to_lds(Kbase + (rowbase + jn*64 + sr + 32*p)*2048 + schf*8,
                              Ks + sb*4096 + p*2048 + wave*512);
                load16_to_lds(Vbase + (size_t)(sr + 32*p)*2048 + jn*64 + schf*8,
                              Vt + sb*4096 + p*2048 + wave*512);
            }
        }

        // ---- S^T[32k x 64q] = K Q^T : A=K-frag, B=Q-frag, d-chained x4 ----
        const int krow = wg*32 + l32;
        const int ksw  = krow & 7;
        f32_16 S[2];
        __builtin_amdgcn_s_setprio(1);
        bf16_8 kf[4];
        #pragma unroll
        for (int df = 0; df < 4; ++df)
            kf[df] = *(const bf16_8*)&Ks[cur*4096 + krow*64 + (((2*df + hh) ^ ksw) << 3)];
        #pragma unroll
        for (int qq = 0; qq < 2; ++qq) {
            f32_16 z;
            #pragma unroll
            for (int r = 0; r < 16; ++r) z[r] = 0.f;
            #pragma unroll
            for (int df = 0; df < 4; ++df)
                z = __builtin_amdgcn_mfma_f32_32x32x16_bf16(kf[df], aq[qq][df], z, 0, 0, 0);
            S[qq] = z;
        }
        __builtin_amdgcn_s_setprio(0);

        // ---- exp2 + causal mask; pack P^T into PV B-frags (VALU only) ----
        const bool diag = (j >= 2*qt);
        unsigned fr[2][8];   // [qtile][khalf*4 + dword]
        #pragma unroll
        for (int qq = 0; qq < 2; ++qq) {
            float pe[16];
            const int qg = qt*128 + wq*64 + qq*32 + l32;
            #pragma unroll
            for (int r = 0; r < 16; ++r) {
                float e = fast_exp2(S[qq][r]);
                if (diag) {
                    int key = j*64 + wg*32 + (r&3) + 8*(r>>2) + 4*hh;
                    if (key > qg) e = 0.f;
                }
                pe[r] = e;
                l_i[qq] += e;
            }
            unsigned A = pk2(pe[0],  pe[1]),  Bv = pk2(pe[2],  pe[3]),
                     C = pk2(pe[4],  pe[5]),  D  = pk2(pe[6],  pe[7]),
                     E = pk2(pe[8],  pe[9]),  F  = pk2(pe[10], pe[11]),
                     G = pk2(pe[12], pe[13]), H  = pk2(pe[14], pe[15]);
            pswap(A, C); pswap(Bv, D); pswap(E, G); pswap(F, H);
            fr[qq][0] = A; fr[qq][1] = Bv; fr[qq][2] = C; fr[qq][3] = D;
            fr[qq][4] = E; fr[qq][5] = F;  fr[qq][6] = G; fr[qq][7] = H;
        }

        // ---- O^T += V^T P^T : A=V-frag (b128), B=P-frag (regs) ----
        __builtin_amdgcn_s_setprio(1);
        #pragma unroll
        for (int kh = 0; kh < 2; ++kh) {
            #pragma unroll
            for (int dt = 0; dt < 2; ++dt) {
                const int d = dt*32 + l32;
                bf16_8 vf = *(const bf16_8*)&Vt[cur*4096 + d*64 +
                                (((wg*4 + kh*2 + hh) ^ (d & 7)) << 3)];
                #pragma unroll
                for (int qq = 0; qq < 2; ++qq) {
                    union { unsigned dw[4]; bf16_8 v; } u;
                    u.dw[0] = fr[qq][kh*4+0]; u.dw[1] = fr[qq][kh*4+1];
                    u.dw[2] = fr[qq][kh*4+2]; u.dw[3] = fr[qq][kh*4+3];
                    O[dt][qq] = __builtin_amdgcn_mfma_f32_32x32x16_bf16(
                        vf, u.v, O[dt][qq], 0, 0, 0);
                }
            }
        }
        __builtin_amdgcn_s_setprio(0);

        cur = (cur == 2) ? 0 : cur + 1;
        sb  = (sb  == 2) ? 0 : sb  + 1;
    }

    // ---- l: own 16 rows + partner half via xor-32 ----
    float lw[2];
    #pragma unroll
    for (int qq = 0; qq < 2; ++qq) {
        float v = l_i[qq];
        v += __shfl_xor(v, 32, 64);
        lw[qq] = v;
    }

    // ---- 2-way wg merge via LDS (Om aliases K/V pool) ----
    __syncthreads();   // all Ks/Vt reads done before Om aliases the pool
    if (wg == 1) {
        #pragma unroll
        for (int qq = 0; qq < 2; ++qq) {
            const int qrow = wq*64 + qq*32 + l32;
            #pragma unroll
            for (int dt = 0; dt < 2; ++dt)
                #pragma unroll
                for (int g = 0; g < 4; ++g) {
                    f32_4 t = { O[dt][qq][g*4+0], O[dt][qq][g*4+1],
                                O[dt][qq][g*4+2], O[dt][qq][g*4+3] };
                    *(f32_4*)&Om[qrow*68 + dt*32 + g*8 + hh*4] = t;
                }
            if (hh == 0) Lm[qrow] = lw[qq];
        }
    }
    __syncthreads();
    if (wg == 0) {
        #pragma unroll
        for (int qq = 0; qq < 2; ++qq) {
            const int qrow = wq*64 + qq*32 + l32;
            const float inv = 1.f / (lw[qq] + Lm[qrow]);
            const size_t obase = (rowbase + qt*128 + qrow) * 1024 + h*64;
            #pragma unroll
            for (int dt = 0; dt < 2; ++dt)
                #pragma unroll
                for (int g = 0; g < 4; ++g) {
                    f32_4 o2 = *(const f32_4*)&Om[qrow*68 + dt*32 + g*8 + hh*4];
                    bf16_4 ov;
                    #pragma unroll
                    for (int r = 0; r < 4; ++r)
                        ov[r] = (__bf16)((O[dt][qq][g*4+r] + o2[r]) * inv);
                    *(bf16_4*)(out + obase + dt*32 + g*8 + hh*4) = ov;
                }
        }
    }
}

// ---------------- launch ----------------
extern "C" void kernel_launch(void* const* d_in, const int* in_sizes, int n_in,
                              void* d_out, int out_size, void* d_ws, size_t ws_size,
                              hipStream_t stream)
{
    constexpr int Bc = 2, Tc = 2048, Dc = 1024;
    constexpr int M  = Bc * Tc;
    constexpr int N1 = 3 * Dc;

    const float* x     = (const float*)d_in[0];
    const float* Wqkv  = (const float*)d_in[1];
    const float* bqkv  = (const float*)d_in[2];
    const float* Wproj = (const float*)d_in[3];
    const float* bproj = (const float*)d_in[4];
    float* outp = (float*)d_out;

    __bf16* xb     = (__bf16*)d_ws;                        // 4096*1024
    __bf16* wqkvb  = xb     + (size_t)M * Dc;              // 3072*1024
    __bf16* wprojb = wqkvb  + (size_t)N1 * Dc;             // 1024*1024
    __bf16* qkb    = wprojb + (size_t)Dc * Dc;             // 4096*2048 (Q|K)
    __bf16* vtb    = qkb    + (size_t)M * 2048;            // 2*1024*2048 (V^T)
    __bf16* attnb  = vtb    + (size_t)Bc * 1024 * 2048;    // 4096*1024

    {
        int na4 = M * Dc / 4, nb4 = N1 * Dc / 4, nc4 = Dc * Dc / 4;
        int n4 = na4 + nb4 + nc4;
        cvt_all<<<(n4 + 255) / 256, 256, 0, stream>>>(x, Wqkv, Wproj, xb, na4, nb4, nc4);
    }

    gemm_bt<1, 128, 1><<<dim3(N1 / 128, M / BM), 256, 0, stream>>>(
        xb, wqkvb, bqkv, qkb, nullptr, vtb, M, N1, Dc, 2048);

    attn_kernel<<<dim3(512), 256, 0, stream>>>(qkb, vtb, attnb);

    gemm_bt<0, 64, 0><<<dim3(Dc / 64, M / BM), 256, 0, stream>>>(
        attnb, wprojb, bproj, nullptr, outp, nullptr, M, Dc, Dc, Dc);
}